// Round 8
// baseline (347.972 us; speedup 1.0000x reference)
//
#include <hip/hip_runtime.h>

// MDTA: B=4, C=384, H=W=128, HEADS=8, D=48
#define HW    16384
#define WD    128
#define CCH   384
#define NB    4
#define NHEAD 8
#define DH    48
#define NCHUNK 16  // score partial chunks (pixels per chunk = HW/NCHUNK = 1024)

typedef unsigned short u16;
typedef unsigned int   u32;
typedef __bf16 bf16x8 __attribute__((ext_vector_type(8)));
typedef float  f32x4  __attribute__((ext_vector_type(4)));

__device__ __forceinline__ float bf2f(u16 u){ u32 t=((u32)u)<<16; float f; __builtin_memcpy(&f,&t,4); return f; }
__device__ __forceinline__ u16 f2bf(float f){ u32 x; __builtin_memcpy(&x,&f,4); u32 r=x+0x7fffu+((x>>16)&1u); return (u16)(r>>16); }
__device__ __forceinline__ f32x4 zero4(){ f32x4 z = {0.f,0.f,0.f,0.f}; return z; }

#define GL16(g,l) __builtin_amdgcn_global_load_lds(\
    (const __attribute__((address_space(1))) void*)(g), \
    (__attribute__((address_space(3))) void*)(l), 16, 0, 0)

// ---------------- prep: cast/concat weights ----------------
__global__ void prep_kernel(const float* wq_p, const float* wk_p, const float* wv_p,
                            const float* bq_p, const float* bk_p, const float* bv_p,
                            const float* wq_d, const float* wk_d, const float* wv_d,
                            const float* bq_d, const float* bk_d, const float* bv_d,
                            u16* Wqkv, float* bias_p, float* wdc, float* bdc)
{
    int idx = blockIdx.x*256 + threadIdx.x;
    const int NW = 3*CCH*CCH;                 // 442368
    if (idx < NW) {
        int m = idx / CCH, c = idx % CCH;
        int w = m / CCH, o = m % CCH;
        const float* src = (w==0)? wq_p : (w==1)? wk_p : wv_p;
        Wqkv[idx] = f2bf(src[o*CCH + c]);
    } else if (idx < NW + 3*CCH) {
        int m = idx - NW; int w = m/CCH, o = m%CCH;
        const float* src = (w==0)? bq_p : (w==1)? bk_p : bv_p;
        bias_p[m] = src[o];
    } else if (idx < NW + 3*CCH + 3*CCH*9) {
        int r = idx - NW - 3*CCH; int m = r/9, k = r%9;
        int w = m/CCH, o = m%CCH;
        const float* src = (w==0)? wq_d : (w==1)? wk_d : wv_d;
        wdc[r] = src[o*9 + k];
    } else if (idx < NW + 3*CCH + 3*CCH*9 + 3*CCH) {
        int m = idx - NW - 3*CCH - 3*CCH*9; int w = m/CCH, o = m%CCH;
        const float* src = (w==0)? bq_d : (w==1)? bk_d : bv_d;
        bdc[m] = src[o];
    }
}

// ---------------- LayerNorm over C per pixel -> xn [b][c][p] AND xn_t [b][p][c] ----------------
// 32 pixels/block (2048 blocks), 256 threads. tx=t&7 pixel-quad, cg=t>>3 owns 12 channels.
// Tile row stride 396 u16 = 792 B (99 x 8B, 99 mod 16 = 3): b64 write slots 3p+3cg and
// read slots 3p+q both cover all 16 dword-pair positions evenly -> conflict-free (b64 floor).
__global__ __launch_bounds__(256) void ln_kernel(
    const float* __restrict__ x, const float* __restrict__ gamma,
    const float* __restrict__ beta, u16* __restrict__ xn, u16* __restrict__ xnt)
{
    __shared__ __align__(16) char lds[32*792 + 512];
    u16* tile    = (u16*)lds;                  // 32 rows x 396 u16
    f32x4* redS  = (f32x4*)lds;                // overlays tile (temporally disjoint)
    f32x4* redS2 = (f32x4*)(lds + 4096);
    float* mu_s  = (float*)(lds + 32*792);     // separate 512B region
    float* rs_s  = mu_s + 32;
    int b  = blockIdx.y;
    int p0 = blockIdx.x*32;
    int t  = threadIdx.x;
    int tx = t & 7, cg = t >> 3;               // pixel quad / channel group of 12
    const float* xb = x + (size_t)b*CCH*HW + p0 + tx*4;
    f32x4 vals[12];
    f32x4 s = zero4(), s2 = zero4();
    #pragma unroll
    for (int cc = 0; cc < 12; ++cc) {
        f32x4 v = *(const f32x4*)(xb + (size_t)(cg*12+cc)*HW);
        vals[cc] = v;
        s += v; s2 += v*v;
    }
    redS[cg*8+tx] = s; redS2[cg*8+tx] = s2;
    __syncthreads();
    if (t < 32) {
        int q = t >> 2, comp = t & 3;
        const float* r1 = (const float*)redS;
        const float* r2 = (const float*)redS2;
        float st = 0.f, st2 = 0.f;
        #pragma unroll
        for (int g2 = 0; g2 < 32; ++g2) {
            st  += r1[(g2*8+q)*4 + comp];
            st2 += r2[(g2*8+q)*4 + comp];
        }
        float mu  = st*(1.f/CCH);
        float var = st2*(1.f/CCH) - mu*mu;
        mu_s[t] = mu;
        rs_s[t] = rsqrtf(var + 1e-5f);
    }
    __syncthreads();
    f32x4 mu4, rs4;
    #pragma unroll
    for (int j = 0; j < 4; ++j) { mu4[j] = mu_s[tx*4+j]; rs4[j] = rs_s[tx*4+j]; }
    u16* xo = xn + (size_t)b*CCH*HW + p0 + tx*4;
    u32 pk[12][2];
    #pragma unroll
    for (int cc = 0; cc < 12; ++cc) {
        int c = cg*12 + cc;
        float gm = gamma[c], bt = beta[c];
        f32x4 v = (vals[cc] - mu4) * rs4;
        u16 o0 = f2bf(v[0]*gm + bt), o1 = f2bf(v[1]*gm + bt);
        u16 o2 = f2bf(v[2]*gm + bt), o3 = f2bf(v[3]*gm + bt);
        u32 w0 = (u32)o0 | ((u32)o1 << 16);
        u32 w1 = (u32)o2 | ((u32)o3 << 16);
        uint2 pkg; pkg.x = w0; pkg.y = w1;
        *(uint2*)(xo + (size_t)c*HW) = pkg;     // NCHW copy
        pk[cc][0] = w0; pk[cc][1] = w1;
    }
    // tile writes (redS region dead after 2nd sync): per pixel, 3 x uint2 (24B of channels)
    #pragma unroll
    for (int i = 0; i < 4; ++i) {
        int row = tx*4 + i;
        char* rp = (char*)tile + row*792 + cg*24;
        #define EXTB(cc) ((pk[cc][i>>1] >> (16*(i&1))) & 0xffffu)
        u32 w0 = EXTB(0)  | (EXTB(1)  << 16);
        u32 w1 = EXTB(2)  | (EXTB(3)  << 16);
        u32 w2 = EXTB(4)  | (EXTB(5)  << 16);
        u32 w3 = EXTB(6)  | (EXTB(7)  << 16);
        u32 w4 = EXTB(8)  | (EXTB(9)  << 16);
        u32 w5 = EXTB(10) | (EXTB(11) << 16);
        #undef EXTB
        uint2 a; a.x = w0; a.y = w1;  *(uint2*)(rp)      = a;
        uint2 bq; bq.x = w2; bq.y = w3; *(uint2*)(rp + 8)  = bq;
        uint2 cq; cq.x = w4; cq.y = w5; *(uint2*)(rp + 16) = cq;
    }
    __syncthreads();
    // copy-out: 32 rows x 96 uint2; consecutive lanes -> consecutive channels (coalesced)
    u16* xto = xnt + (size_t)b*CCH*HW;
    #pragma unroll
    for (int k = 0; k < 12; ++k) {
        int idx = t + k*256;
        int p = idx / 96, q = idx % 96;
        *(uint2*)(xto + (size_t)(p0+p)*CCH + q*4) = *(const uint2*)((char*)tile + p*792 + q*8);
    }
}

// ---------------- NT MFMA GEMM: C[m][n] = sum_k A[m][k]*B[n][k]  (K=384) ----------------
// 128x128 tile, BK=64, 8 waves (64x32 each).
// TRANSB=0: single-buffer 32KB, GL16 both operands (r3-proven structure).
// TRANSB=1: B=[k][n] (V in [c][p]). Full dbuf (A GL16 + B reg-staged, 64KB) with
//   T3/T4 schedule: raw s_barrier + counted vmcnt; V prefetched 2 K-steps ahead in
//   two register sets so the HBM V-loads stay in flight ACROSS the barrier.
// EPI 0: +bias, store bf16 (row-stride HW).
// EPI 1: +bias +xn(bf16), store f32 via LDS-shuffled vectorized epilogue.
template<int EPI, int TRANSB>
__global__ __launch_bounds__(512) void gemm_nt(
    const u16* __restrict__ A, const u16* __restrict__ Bm, void* __restrict__ Cout,
    const float* __restrict__ bias, const u16* __restrict__ xnadd,
    long A_bstride, long B_bstride, long C_bstride)
{
    constexpr int SMBYTES = TRANSB ? 65536 : 32768;
    __shared__ __align__(16) char smraw[SMBYTES];
    u16* smA = (u16*)smraw;                               // TRANSB=1: 2 x 16KB dbuf
    u16* smB = (u16*)(smraw + (TRANSB ? 32768 : 16384));  // TRANSB=1: 2 x 16KB dbuf
    int b  = blockIdx.z;
    int m0 = blockIdx.x*128, n0 = blockIdx.y*128;
    const u16* Ab = A  + (size_t)b*A_bstride;
    const u16* Bb = Bm + (size_t)b*B_bstride;
    int t = threadIdx.x;
    int lane = t & 63, w = t >> 6;
    int wr = w >> 2, wc = w & 3;              // rows wr*64.., cols wc*32..
    int l15 = lane & 15, g = lane >> 4;
    int s7 = l15 & 7;

    int rowA[2], kksA[2];
    #pragma unroll
    for (int r = 0; r < 2; ++r) {
        int e = (r*512 + t)*8;
        rowA[r] = e >> 6;
        int kk  = e & 63;
        kksA[r] = kk ^ ((rowA[r]&7)<<3);      // pre-swizzle source -> linear LDS dest is swizzled
    }
    // TRANSB=1 reg-staging coords: thread owns channels (cB, cB+1) x 8 pixels
    int cB  = (2*t) & 63;                     // even
    int pxg = (2*t) >> 6;                     // 0..15

    f32x4 acc[4][2];
    #pragma unroll
    for (int i=0;i<4;++i) { acc[i][0] = zero4(); acc[i][1] = zero4(); }

#define COMPUTE(sAp, sBp) { \
    const u16* sA_ = (sAp); const u16* sB_ = (sBp); \
    _Pragma("unroll") \
    for (int kh = 0; kh < 2; ++kh) { \
        int u = (kh*4 + g) ^ s7; \
        bf16x8 af[4], bq[2]; \
        _Pragma("unroll") \
        for (int mi=0;mi<4;++mi) { \
            int row = wr*64 + mi*16 + l15; \
            af[mi] = *(const bf16x8*)&sA_[row*64 + u*8]; \
        } \
        _Pragma("unroll") \
        for (int nj=0;nj<2;++nj) { \
            int row = wc*32 + nj*16 + l15; \
            bq[nj] = *(const bf16x8*)&sB_[row*64 + u*8]; \
        } \
        _Pragma("unroll") \
        for (int mi=0;mi<4;++mi) \
            _Pragma("unroll") \
            for (int nj=0;nj<2;++nj) \
                acc[mi][nj] = __builtin_amdgcn_mfma_f32_16x16x32_bf16(af[mi], bq[nj], acc[mi][nj], 0,0,0); \
    } }

#define WRITE_SMB(dst, va, vb) { \
    u16 e0[8], e1[8]; \
    __builtin_memcpy(e0,&(va),16); __builtin_memcpy(e1,&(vb),16); \
    _Pragma("unroll") \
    for (int j=0;j<8;++j) { \
        u32 wv = (u32)e0[j] | ((u32)e1[j]<<16); \
        *(u32*)((dst) + (pxg*8+j)*64 + (cB ^ (j<<3))) = wv; \
    } }

    if (!TRANSB) {
        // ---- r3-proven single-buffer 2-barrier loop ----
        #pragma unroll
        for (int r = 0; r < 2; ++r) {
            GL16(Ab + (size_t)(m0+rowA[r])*CCH + kksA[r], smA + r*4096 + w*512);
            GL16(Bb + (size_t)(n0+rowA[r])*CCH + kksA[r], smB + r*4096 + w*512);
        }
        __syncthreads();
        for (int ks = 0; ks < 6; ++ks) {
            COMPUTE(smA, smB);
            if (ks < 5) {
                __syncthreads();
                int k1 = (ks+1)*64;
                #pragma unroll
                for (int r = 0; r < 2; ++r) {
                    GL16(Ab + (size_t)(m0+rowA[r])*CCH + k1 + kksA[r], smA + r*4096 + w*512);
                    GL16(Bb + (size_t)(n0+rowA[r])*CCH + k1 + kksA[r], smB + r*4096 + w*512);
                }
                __syncthreads();
            }
        }
    } else {
        // ---- pipelined: dbuf + raw barrier + counted vmcnt; V 2-deep in regs ----
        uint4 s0a, s0b, s1a, s1b;
        // prologue: V(k0) -> set0, A(k0) -> smA[0]
        s0a = *(const uint4*)(Bb + (size_t)cB*HW     + n0 + pxg*8);
        s0b = *(const uint4*)(Bb + (size_t)(cB+1)*HW + n0 + pxg*8);
        #pragma unroll
        for (int r = 0; r < 2; ++r)
            GL16(Ab + (size_t)(m0+rowA[r])*CCH + kksA[r], smA + r*4096 + w*512);
        WRITE_SMB(smB, s0a, s0b);             // compiler auto-waits set0
        s1a = *(const uint4*)(Bb + (size_t)(64+cB)*HW   + n0 + pxg*8);   // V(k1) -> set1
        s1b = *(const uint4*)(Bb + (size_t)(64+cB+1)*HW + n0 + pxg*8);
        asm volatile("s_waitcnt vmcnt(2)" ::: "memory");   // A done; set1 V stays in flight
        asm volatile("s_waitcnt lgkmcnt(0)" ::: "memory");
        __builtin_amdgcn_sched_barrier(0);
        __builtin_amdgcn_s_barrier();

        #pragma unroll
        for (int ks = 0; ks < 6; ++ks) {
            int cur = ks & 1, nxt = cur ^ 1;
            if (ks < 5) {                      // A for ks+1 (L2-hot wf_eff)
                int k1 = (ks+1)*64;
                #pragma unroll
                for (int r = 0; r < 2; ++r)
                    GL16(Ab + (size_t)(m0+rowA[r])*CCH + k1 + kksA[r],
                         smA + nxt*8192 + r*4096 + w*512);
            }
            if (ks < 4) {                      // V for ks+2 into the freed set
                int k2 = (ks+2)*64;
                if ((ks & 1) == 0) {
                    s0a = *(const uint4*)(Bb + (size_t)(k2+cB)*HW   + n0 + pxg*8);
                    s0b = *(const uint4*)(Bb + (size_t)(k2+cB+1)*HW + n0 + pxg*8);
                } else {
                    s1a = *(const uint4*)(Bb + (size_t)(k2+cB)*HW   + n0 + pxg*8);
                    s1b = *(const uint4*)(Bb + (size_t)(k2+cB+1)*HW + n0 + pxg*8);
                }
            }
            COMPUTE(smA + cur*8192, smB + cur*8192);
            if (ks < 5) {
                if (((ks+1) & 1) == 0) { WRITE_SMB(smB + nxt*8192, s0a, s0b); }
                else                   { WRITE_SMB(smB + nxt*8192, s1a, s1b); }
                if (ks < 4) asm volatile("s_waitcnt vmcnt(2)" ::: "memory");  // A drained, V(ks+2) in flight
                else        asm volatile("s_waitcnt vmcnt(0)" ::: "memory");
                asm volatile("s_waitcnt lgkmcnt(0)" ::: "memory");
                __builtin_amdgcn_sched_barrier(0);
                __builtin_amdgcn_s_barrier();
            }
        }
    }

    if (EPI == 0) {
        #pragma unroll
        for (int mi=0;mi<4;++mi) {
            #pragma unroll
            for (int r=0;r<4;++r) {
                int grow = m0 + wr*64 + mi*16 + g*4 + r;
                float bv = bias[grow];
                #pragma unroll
                for (int nj=0;nj<2;++nj) {
                    int gcol = n0 + wc*32 + nj*16 + l15;
                    ((u16*)Cout)[(size_t)b*C_bstride + (size_t)grow*HW + gcol] = f2bf(acc[mi][nj][r] + bv);
                }
            }
        }
    } else {
        // LDS-shuffled epilogue: two halves of 64 LDS-rows (mi pairs), vectorized f32x4 stores.
        float* epi = (float*)smraw;           // 64 x 132 f32 = 33792 B
        #pragma unroll
        for (int half = 0; half < 2; ++half) {
            __syncthreads();                  // protect smraw / prior half reads
            #pragma unroll
            for (int mi2 = 0; mi2 < 2; ++mi2) {
                int mi = half*2 + mi2;
                #pragma unroll
                for (int r = 0; r < 4; ++r) {
                    int lrow = wr*32 + mi2*16 + g*4 + r;
                    int grow = m0 + wr*64 + half*32 + mi2*16 + g*4 + r;
                    float bv = bias[grow];
                    #pragma unroll
                    for (int nj = 0; nj < 2; ++nj)
                        epi[lrow*132 + wc*32 + nj*16 + l15] = acc[mi][nj][r] + bv;
                }
            }
            __syncthreads();
            #pragma unroll
            for (int k = 0; k < 4; ++k) {
                int idx = t + k*512;
                int lrow = idx >> 5, cq = idx & 31;
                int grow = m0 + (lrow>>5)*64 + half*32 + (lrow&31);
                int gcol = n0 + cq*4;
                f32x4 v = *(const f32x4*)&epi[lrow*132 + cq*4];
                uint2 xv = *(const uint2*)(xnadd + (size_t)b*CCH*HW + (size_t)grow*HW + gcol);
                v[0] += bf2f((u16)xv.x);        v[1] += bf2f((u16)(xv.x>>16));
                v[2] += bf2f((u16)xv.y);        v[3] += bf2f((u16)(xv.y>>16));
                *(f32x4*)((float*)Cout + (size_t)b*C_bstride + (size_t)grow*HW + gcol) = v;
            }
        }
    }
#undef COMPUTE
#undef WRITE_SMB
}

// ---------------- depthwise 3x3 SAME, bf16 in/out, [b][cpb][p] ----------------
__global__ void dw_kernel(const u16* __restrict__ in, u16* __restrict__ out,
                          const float* __restrict__ wd, const float* __restrict__ bd,
                          int cpb)
{
    int b  = blockIdx.z;
    int c  = blockIdx.y;
    int yt = blockIdx.x;
    int t  = threadIdx.x;
    int ty = t >> 4, tx = t & 15;
    int y  = yt*16 + ty;
    int x0 = tx*8;
    const u16* ib = in + (size_t)b*cpb*HW + (size_t)c*HW;
    float w9[9];
    #pragma unroll
    for (int i=0;i<9;++i) w9[i] = wd[c*9+i];
    float bv = bd[c];
    float rows[3][10];
    #pragma unroll
    for (int dy=0; dy<3; ++dy) {
        int yy = y + dy - 1;
        if (yy < 0 || yy >= WD) { for (int i=0;i<10;++i) rows[dy][i]=0.f; continue; }
        const u16* rp = ib + yy*WD;
        rows[dy][0] = (x0==0) ? 0.f : bf2f(rp[x0-1]);
        uint4 v = *(const uint4*)(rp + x0);
        u16 e[8]; __builtin_memcpy(e,&v,16);
        #pragma unroll
        for (int i=0;i<8;++i) rows[dy][1+i] = bf2f(e[i]);
        rows[dy][9] = (x0+8 >= WD) ? 0.f : bf2f(rp[x0+8]);
    }
    u16 ovals[8];
    #pragma unroll
    for (int xo=0; xo<8; ++xo) {
        float a = bv;
        #pragma unroll
        for (int dy=0;dy<3;++dy)
            #pragma unroll
            for (int dx=0;dx<3;++dx)
                a += rows[dy][xo+dx] * w9[dy*3+dx];
        ovals[xo] = f2bf(a);
    }
    uint4 ov; __builtin_memcpy(&ov, ovals, 16);
    *(uint4*)(out + (size_t)b*cpb*HW + (size_t)c*HW + y*WD + x0) = ov;
}

// ---------------- scores partials: S[i][j] += sum_p K[i,p]*Q[j,p] over a pixel chunk ----------------
__global__ void scores_kernel(const u16* __restrict__ Kp, const u16* __restrict__ Qp,
                              float* __restrict__ S_part, int cpb)
{
    int pc = blockIdx.x;                      // 0..NCHUNK-1 pixel chunks
    int h  = blockIdx.y;
    int b  = blockIdx.z;
    int lane = threadIdx.x;                   // 64
    int l15 = lane & 15, g = lane >> 4;
    const u16* Kb = Kp + (size_t)b*cpb*HW + (size_t)(h*DH)*HW;
    const u16* Qb = Qp + (size_t)b*cpb*HW + (size_t)(h*DH)*HW;
    int p0 = pc*(HW/NCHUNK);
    f32x4 acc[3][3];
    #pragma unroll
    for (int i=0;i<3;++i)
        #pragma unroll
        for (int j=0;j<3;++j) acc[i][j] = zero4();
    for (int kk=0; kk<(HW/NCHUNK)/32; ++kk) {
        int p = p0 + kk*32 + g*8;
        bf16x8 af[3], bq[3];
        #pragma unroll
        for (int it=0; it<3; ++it)
            af[it] = *(const bf16x8*)(Kb + (size_t)(it*16 + l15)*HW + p);
        #pragma unroll
        for (int jt=0; jt<3; ++jt)
            bq[jt] = *(const bf16x8*)(Qb + (size_t)(jt*16 + l15)*HW + p);
        #pragma unroll
        for (int it=0;it<3;++it)
            #pragma unroll
            for (int jt=0;jt<3;++jt)
                acc[it][jt] = __builtin_amdgcn_mfma_f32_16x16x32_bf16(af[it], bq[jt], acc[it][jt], 0,0,0);
    }
    float* Sp = S_part + ((size_t)pc*32 + b*NHEAD + h)*(DH*DH);
    #pragma unroll
    for (int it=0;it<3;++it)
        #pragma unroll
        for (int jt=0;jt<3;++jt)
            #pragma unroll
            for (int r=0;r<4;++r) {
                int i = it*16 + g*4 + r;
                int j = jt*16 + l15;
                Sp[i*DH + j] = acc[it][jt][r];
            }
}

// ---------------- reduce partials + softmax over j ----------------
__global__ void sm_kernel(const float* __restrict__ S_part, const float* __restrict__ alpha,
                          float* __restrict__ soft)
{
    __shared__ float S[DH*DH];
    int bh = blockIdx.x;                      // b*8+h
    int h  = bh & 7;
    int t  = threadIdx.x;                     // 256
    float ia = 1.f / alpha[h];
    for (int e = t; e < DH*DH; e += 256) {
        float s = 0.f;
        #pragma unroll
        for (int pc=0; pc<NCHUNK; ++pc) s += S_part[((size_t)pc*32 + bh)*(DH*DH) + e];
        S[e] = s * ia;
    }
    __syncthreads();
    if (t < DH) {
        float m = -1e30f;
        for (int j=0;j<DH;++j) m = fmaxf(m, S[t*DH+j]);
        float sum = 0.f;
        for (int j=0;j<DH;++j) sum += __expf(S[t*DH+j]-m);
        float inv = 1.f/sum;
        for (int j=0;j<DH;++j)
            soft[(size_t)bh*(DH*DH) + t*DH + j] = __expf(S[t*DH+j]-m)*inv;
    }
}

// ---------------- fold softmax into wf (LDS-tiled) ----------------
// wf_eff[b][o][n*48+i] = sum_j wf[o][n*48+j]*soft[b,n,i,j]
__global__ __launch_bounds__(256) void fold_kernel(const float* __restrict__ wf,
                                                   const float* __restrict__ soft,
                                                   u16* __restrict__ wf_eff)
{
    __shared__ float softl[DH*DH];            // 9216 B
    __shared__ float wfl[16*DH];              // 3072 B
    int ob = blockIdx.x, h = blockIdx.y, b = blockIdx.z;
    int t = threadIdx.x;
    const float* sb = soft + ((size_t)(b*NHEAD + h))*(DH*DH);
    for (int k = t; k < DH*DH; k += 256) softl[k] = sb[k];
    for (int k = t; k < 16*DH; k += 256) {
        int ol = k / DH, j = k % DH;
        wfl[k] = wf[(size_t)(ob*16 + ol)*CCH + h*DH + j];
    }
    __syncthreads();
    #pragma unroll
    for (int r = 0; r < 3; ++r) {
        int out = r*256 + t;                  // 0..767
        int ol = out / DH, i = out % DH;
        const f32x4* wr_ = (const f32x4*)&wfl[ol*DH];
        const f32x4* sr  = (const f32x4*)&softl[i*DH];
        f32x4 a4 = zero4();
        #pragma unroll
        for (int j = 0; j < 12; ++j) a4 += wr_[j]*sr[j];
        float a = a4[0]+a4[1]+a4[2]+a4[3];
        wf_eff[((size_t)b*CCH + ob*16 + ol)*CCH + h*DH + i] = f2bf(a);
    }
}

extern "C" void kernel_launch(void* const* d_in, const int* in_sizes, int n_in,
                              void* d_out, int out_size, void* d_ws, size_t ws_size,
                              hipStream_t stream)
{
    const float* x    = (const float*)d_in[0];
    const float* ln_g = (const float*)d_in[1];
    const float* ln_b = (const float*)d_in[2];
    const float* wq_p = (const float*)d_in[3];
    const float* bq_p = (const float*)d_in[4];
    const float* wq_d = (const float*)d_in[5];
    const float* bq_d = (const float*)d_in[6];
    const float* wk_p = (const float*)d_in[7];
    const float* bk_p = (const float*)d_in[8];
    const float* wk_d = (const float*)d_in[9];
    const float* bk_d = (const float*)d_in[10];
    const float* wv_p = (const float*)d_in[11];
    const float* bv_p = (const float*)d_in[12];
    const float* wv_d = (const float*)d_in[13];
    const float* bv_d = (const float*)d_in[14];
    const float* alpha= (const float*)d_in[15];
    const float* wf   = (const float*)d_in[16];
    const float* bf_  = (const float*)d_in[17];

    char* ws = (char*)d_ws;
    size_t off = 0;
    auto alloc = [&](size_t bytes)->char* { char* p = ws + off; off += (bytes + 255) & ~(size_t)255; return p; };
    const size_t BIG  = (size_t)NB*CCH*HW*2;       // 50.3 MB bf16 [b][384][16384]
    const size_t BIG3 = 3*BIG;                     // 151 MB   [b][1152][16384]
    const size_t SMALLS = (size_t)3*CCH*CCH*2 + 3*CCH*4 + 3*CCH*9*4 + 3*CCH*4
                        + (size_t)NCHUNK*32*DH*DH*4 + (size_t)32*DH*DH*4
                        + (size_t)NB*CCH*CCH*2 + 16*256;
    const size_t NEED_FUSED = 2*BIG + 2*BIG3 + SMALLS;
    const bool fused = (ws_size >= NEED_FUSED);
    const long BStr = (long)CCH*HW;

    if (fused) {
        u16* xn_cp  = (u16*)alloc(BIG);
        u16* xn_t   = (u16*)alloc(BIG);
        u16* pwQKV  = (u16*)alloc(BIG3);
        u16* dwQKV  = (u16*)alloc(BIG3);
        u16*   Wqkv   = (u16*)  alloc((size_t)3*CCH*CCH*2);
        float* bias_p = (float*)alloc((size_t)3*CCH*4);
        float* wdc    = (float*)alloc((size_t)3*CCH*9*4);
        float* bdc    = (float*)alloc((size_t)3*CCH*4);
        float* S_part = (float*)alloc((size_t)NCHUNK*32*DH*DH*4);
        float* soft   = (float*)alloc((size_t)32*DH*DH*4);
        u16*   wf_eff = (u16*)  alloc((size_t)NB*CCH*CCH*2);

        prep_kernel<<<1778, 256, 0, stream>>>(wq_p,wk_p,wv_p, bq_p,bk_p,bv_p,
                                              wq_d,wk_d,wv_d, bq_d,bk_d,bv_d,
                                              Wqkv, bias_p, wdc, bdc);
        ln_kernel<<<dim3(512,NB), 256, 0, stream>>>(x, ln_g, ln_b, xn_cp, xn_t);
        // fused QKV pointwise: M=1152
        gemm_nt<0,0><<<dim3(9,128,NB), 512, 0, stream>>>(Wqkv, xn_t, pwQKV, bias_p, nullptr,
                                                         0, BStr, (long)3*CCH*HW);
        dw_kernel<<<dim3(8,3*CCH,NB), 256, 0, stream>>>(pwQKV, dwQKV, wdc, bdc, 3*CCH);
        scores_kernel<<<dim3(NCHUNK,NHEAD,NB), 64, 0, stream>>>(dwQKV + (size_t)CCH*HW,  // K
                                                                dwQKV,                   // Q
                                                                S_part, 3*CCH);
        sm_kernel<<<32, 256, 0, stream>>>(S_part, alpha, soft);
        fold_kernel<<<dim3(CCH/16, NHEAD, NB), 256, 0, stream>>>(wf, soft, wf_eff);
        // final: x_cap = wf_eff x V + bf + xn ; V consumed directly in [c][p] (TRANSB=1)
        gemm_nt<1,1><<<dim3(3,128,NB), 512, 0, stream>>>(wf_eff, dwQKV + (size_t)2*CCH*HW,
                                                         d_out, bf_, xn_cp,
                                                         (long)CCH*CCH, (long)3*CCH*HW, BStr);
    } else {
        u16* xn_cp = (u16*)alloc(BIG);
        u16* xn_t  = (u16*)alloc(BIG);
        u16* pwA   = (u16*)alloc(BIG);
        u16* dwQ   = (u16*)alloc(BIG);
        u16* dwK   = (u16*)alloc(BIG);
        u16*   Wqkv   = (u16*)  alloc((size_t)3*CCH*CCH*2);
        float* bias_p = (float*)alloc((size_t)3*CCH*4);
        float* wdc    = (float*)alloc((size_t)3*CCH*9*4);
        float* bdc    = (float*)alloc((size_t)3*CCH*4);
        float* S_part = (float*)alloc((size_t)NCHUNK*32*DH*DH*4);
        float* soft   = (float*)alloc((size_t)32*DH*DH*4);
        u16*   wf_eff = (u16*)  alloc((size_t)NB*CCH*CCH*2);
        if (off > ws_size) return;
        u16* dwV = dwQ;                        // dwQ dead after scores

        prep_kernel<<<1778, 256, 0, stream>>>(wq_p,wk_p,wv_p, bq_p,bk_p,bv_p,
                                              wq_d,wk_d,wv_d, bq_d,bk_d,bv_d,
                                              Wqkv, bias_p, wdc, bdc);
        ln_kernel<<<dim3(512,NB), 256, 0, stream>>>(x, ln_g, ln_b, xn_cp, xn_t);
        gemm_nt<0,0><<<dim3(3,128,NB), 512, 0, stream>>>(Wqkv,           xn_t, pwA, bias_p,       nullptr, 0, BStr, BStr);
        dw_kernel<<<dim3(8,CCH,NB), 256, 0, stream>>>(pwA, dwQ, wdc,         bdc,       CCH);
        gemm_nt<0,0><<<dim3(3,128,NB), 512, 0, stream>>>(Wqkv + CCH*CCH, xn_t, pwA, bias_p + CCH, nullptr, 0, BStr, BStr);
        dw_kernel<<<dim3(8,CCH,NB), 256, 0, stream>>>(pwA, dwK, wdc + CCH*9, bdc + CCH, CCH);
        scores_kernel<<<dim3(NCHUNK,NHEAD,NB), 64, 0, stream>>>(dwK, dwQ, S_part, CCH);
        sm_kernel<<<32, 256, 0, stream>>>(S_part, alpha, soft);
        fold_kernel<<<dim3(CCH/16, NHEAD, NB), 256, 0, stream>>>(wf, soft, wf_eff);
        gemm_nt<0,0><<<dim3(3,128,NB), 512, 0, stream>>>(Wqkv + 2*CCH*CCH, xn_t, pwA, bias_p + 2*CCH, nullptr, 0, BStr, BStr);
        dw_kernel<<<dim3(8,CCH,NB), 256, 0, stream>>>(pwA, dwV, wdc + 2*CCH*9, bdc + 2*CCH, CCH);
        gemm_nt<1,1><<<dim3(3,128,NB), 512, 0, stream>>>(wf_eff, dwV, d_out, bf_, xn_cp,
                                                         (long)CCH*CCH, BStr, BStr);
    }
}